// Round 6
// baseline (441.798 us; speedup 1.0000x reference)
//
#include <hip/hip_runtime.h>
#include <hip/hip_bf16.h>
#include <math.h>

#define GS 1024
#define BSZ 256
#define DD 128
#define NEGV -1e30f

typedef __attribute__((ext_vector_type(8))) short bf16x8_t;
typedef __attribute__((ext_vector_type(4))) float f32x4_t;
typedef __attribute__((ext_vector_type(2))) float f32x2_t;

// ---- workspace layout (bytes) ---- (identical to proven 405us layout)
#define WGRU_OFF_BYTES 131072
#define WQP_OFF_BYTES  524288
#define WIHB_OFF_BYTES 655360
#define F_OFF_BYTES    688128
// float offsets inside F:
#define FH_HM   0        // 262144  h-mean partials [b][seg][d]
#define FI_V    262144   // 65536   [b][256] V1|V2
#define FJ_AQB  327680   // 524288  [b][d][j][sel]  sel = {a1,b1,a2,b2}
#define FK_RES  851968   // 1048576 [b][j][g]  (atomically accumulated by 2 half-blocks)
#define F_TOTAL 1900544
#define DESC_OFF_BYTES (F_OFF_BYTES + F_TOTAL * 4)   // int [b][32]
// optional region (only touched when ws_size >= WS_NEED):
// bf16 h image, MFMA-fragment-swizzled:
//   hbw[(((b*64 + T)*4 + kt)*64 + lane)*8 + j] = h[b][T*16 + (lane&15)][kt*32 + (lane>>4)*8 + j]
#define HBF_OFF_BYTES  (DESC_OFF_BYTES + 32768)      // 64 MB
#define WS_NEED ((size_t)HBF_OFF_BYTES + (size_t)BSZ * GS * DD * 2)

__device__ __forceinline__ float rtanh(float x) {
    float s = fmaf(x, x, 1.0f);
    return x * __builtin_amdgcn_rsqf(s);
}
__device__ __forceinline__ float tanh2(float x) {
    float e = __expf(x + x);
    return fmaf(-2.0f, __builtin_amdgcn_rcpf(e + 1.0f), 1.0f);
}
__device__ __forceinline__ float sigm2(float x) {
    return __builtin_amdgcn_rcpf(1.0f + __expf(-x));
}
__device__ __forceinline__ unsigned short f2bf(float f) {
    union { float f; unsigned u; } v; v.f = f;
    unsigned u = v.u;
    return (unsigned short)((u + 0x7fffu + ((u >> 16) & 1u)) >> 16);
}
#define MFMA16(a, b, c) __builtin_amdgcn_mfma_f32_16x16x32_bf16((a), (b), (c), 0, 0, 0)

// ---------------- kernel A: fused hmean (+ gated swizzled h->bf16) + pack ----
__global__ __launch_bounds__(128) void init_kernel(
    const float* __restrict__ h,
    const float* __restrict__ wk1, const float* __restrict__ wk2,
    const float* __restrict__ wk3, const float* __restrict__ wk4,
    const float* __restrict__ wq1, const float* __restrict__ wq2,
    const float* __restrict__ wq3, const float* __restrict__ wq4,
    const float* __restrict__ ihw,
    const float* __restrict__ r1ih, const float* __restrict__ r1hh,
    const float* __restrict__ r2ih, const float* __restrict__ r2hh,
    unsigned short* __restrict__ wbf, unsigned short* __restrict__ wgru,
    unsigned short* __restrict__ wqp, unsigned short* __restrict__ wihb,
    float* __restrict__ F, unsigned short* __restrict__ hbw, int use_hbf)
{
    if (blockIdx.x < 2048) {
        int b = blockIdx.x >> 3, seg = blockIdx.x & 7;
        int t = threadIdx.x;
        int rg = t >> 4, c = t & 15;
        int kt = c >> 2, quad = c & 3;
        // skewed LDS image: chunk q (16B) lives at byte (q + (q>>4)) * 16
        __shared__ __attribute__((aligned(16))) unsigned short lim[17408]; // 34816 B
        __shared__ float cs[8][128];
        float s0=0.f,s1=0.f,s2=0.f,s3=0.f,s4=0.f,s5=0.f,s6=0.f,s7=0.f;
#pragma unroll
        for (int i = 0; i < 16; i++) {
            int rl = rg + 8 * i;
            const float* src = h + ((size_t)(b * GS + seg * 128 + rl)) * DD + c * 8;
            f32x4_t lo = *(const f32x4_t*)src;
            f32x4_t hi = *(const f32x4_t*)(src + 4);
            s0 += lo[0]; s1 += lo[1]; s2 += lo[2]; s3 += lo[3];
            s4 += hi[0]; s5 += hi[1]; s6 += hi[2]; s7 += hi[3];
            if (use_hbf) {
                int tt = rl >> 4, ml = rl & 15;
                union { unsigned short s[8]; bf16x8_t v; } pk;
                pk.s[0] = f2bf(lo[0]); pk.s[1] = f2bf(lo[1]);
                pk.s[2] = f2bf(lo[2]); pk.s[3] = f2bf(lo[3]);
                pk.s[4] = f2bf(hi[0]); pk.s[5] = f2bf(hi[1]);
                pk.s[6] = f2bf(hi[2]); pk.s[7] = f2bf(hi[3]);
                int q = tt * 256 + kt * 64 + quad * 16 + ml;   // local chunk idx
                int ob16 = q + (q >> 4);                        // skew: +16B per 256B
                *(bf16x8_t*)&lim[ob16 * 8] = pk.v;
            }
        }
        cs[rg][c * 8 + 0] = s0; cs[rg][c * 8 + 1] = s1;
        cs[rg][c * 8 + 2] = s2; cs[rg][c * 8 + 3] = s3;
        cs[rg][c * 8 + 4] = s4; cs[rg][c * 8 + 5] = s5;
        cs[rg][c * 8 + 6] = s6; cs[rg][c * 8 + 7] = s7;
        __syncthreads();
        {
            int d = t;
            float s = 0.0f;
#pragma unroll
            for (int k = 0; k < 8; k++) s += cs[k][d];
            F[FH_HM + b * 1024 + seg * 128 + d] = s;
        }
        if (use_hbf) {
            unsigned short* dst = hbw + ((size_t)(b * 64 + seg * 8)) * 2048;
#pragma unroll
            for (int it = 0; it < 16; it++) {
                int e = it * 128 + t;
                int ob16 = e + (e >> 4);
                bf16x8_t v = *(const bf16x8_t*)&lim[ob16 * 8];
                *(bf16x8_t*)(dst + (size_t)e * 8) = v;   // linear, coalesced
            }
        }
        return;
    }
    int tid = (blockIdx.x - 2048) * 128 + threadIdx.x;
    int nth = 128 * 128;
    const float* wks[4]  = {wk1, wk2, wk3, wk4};
    const float* rws[4]  = {r1ih, r1hh, r2ih, r2hh};
    const float* wqs2[4] = {wq1, wq3, wq2, wq4};

    for (int e = tid; e < 65536; e += nth)            // W_K bf16 [mat][d][k]
        wbf[e] = f2bf(wks[e >> 14][e & 16383]);
    for (int e = tid; e < 196608; e += nth)           // GRU weights row-major
        wgru[e] = f2bf(rws[e / 49152][e % 49152]);
    for (int e = tid; e < 65536; e += nth)            // WQ pairs row-major
        wqp[e] = f2bf(wqs2[e >> 14][e & 16383]);
    for (int e = tid; e < 16384; e += nth)            // init_hidden_W row-major [d][k]
        wihb[e] = f2bf(ihw[e]);
    for (int e = tid; e < 1048576; e += nth)          // zero FK_RES for atomic accum
        F[FK_RES + e] = 0.0f;
}

// ---------------- kernel B: fused prep + 4 GRU steps + AQ (proven version) ---
__global__ __launch_bounds__(512) void prep_kernel(
    const float* __restrict__ h, const float* __restrict__ ctx2,
    const int* __restrict__ rec, const int* __restrict__ vt,
    const int* __restrict__ la_, const int* __restrict__ fa,
    const float* __restrict__ mW1, const float* __restrict__ mb1,
    const float* __restrict__ mW2, const float* __restrict__ mb2,
    const float* __restrict__ ihb, const float* __restrict__ iq,
    const float* __restrict__ b1ih, const float* __restrict__ b1hh,
    const float* __restrict__ b2ih, const float* __restrict__ b2hh,
    const unsigned short* __restrict__ wgru, const unsigned short* __restrict__ wqp,
    const unsigned short* __restrict__ wihb,
    float* __restrict__ F, int* __restrict__ DESC, float* __restrict__ out)
{
    int rho = blockIdx.x & 1;
    int b0  = (blockIdx.x >> 1) * 16;
    int t = threadIdx.x;
    int lane = t & 63, w = t >> 6, ml = lane & 15, quad = lane >> 4;
    int dloc = w * 16 + ml;     // this lane's d

    __shared__ __attribute__((aligned(16))) unsigned short hmb[16][136];
    __shared__ __attribute__((aligned(16))) unsigned short Xall[4][16][136];
    __shared__ __attribute__((aligned(16))) unsigned short Qb[2][16][136];
    __shared__ float hid[16][8];
    __shared__ int sdesc[16][26];

    const float* bih = rho ? b2ih : b1ih;
    const float* bhh = rho ? b2hh : b1hh;

    // ---- phase 0: hm sums, meta hidden, int machine (independent) ----
#pragma unroll
    for (int k = 0; k < 4; k++) {
        int e = t + 512 * k;               // 2048 = 16b x 128d
        int b = e >> 7, d = e & 127;
        float s = 0.0f;
#pragma unroll
        for (int seg = 0; seg < 8; seg++)
            s += F[FH_HM + (b0 + b) * 1024 + seg * 128 + d];
        hmb[b][d] = f2bf(s * (1.0f / 1024.0f));
    }
    if (t < 128) {
        int b = t >> 3, u = t & 7;
        float a = mb1[u];
        for (int k = 0; k < 9; k++) a += mW1[u * 9 + k] * ctx2[(b0 + b) * 9 + k];
        hid[b][u] = a > 0.0f ? a : 0.0f;
    }
    if (rho == 0 && t >= 144 && t < 160)    // zero ll accumulators for finalize
        out[3072 + b0 + (t - 144)] = 0.0f;
    if (t >= 128 && t < 144) {
        int tb = t - 128;
        int b = b0 + tb;
        int ai[4], kal[5] = {0, 0, 0, 0, 0}, kar[4] = {0, 0, 0, 0};
        int idesc[26];
        int stopped = 1, nola = -1, vt0 = 0;
        for (int i = 0; i < 4; i++) {
            idesc[16 + i] = stopped;
            idesc[22 + i] = nola;
            int action = fa[b * 4 + i];
            if (i > 0 && stopped) action = ai[0];
            int nona = rec[b * GS + action];
            ai[i] = action;
            if (stopped) kal[i] = action;
            int jprev = (i + 3) & 3;
            if (!stopped) kar[jprev] = action;
            kal[i + 1] = nona;
            int hit = (action == nola) ? 1 : 0;
            int st = (i > 0) ? (stopped | hit) : hit;
            if (st) kal[i] = kal[(i + 4) % 5];
            if (st) kar[i] = kar[jprev];
            if (i == 0) vt0 = vt[b * GS + action];
            idesc[0 + i]  = action;
            idesc[4 + i]  = (vt[b * GS + action] - vt0) & (GS - 1);
            idesc[8 + i]  = st;
            idesc[12 + i] = (!st && (nona == ai[0])) ? 1 : 0;
            nola = st ? -1 : nona;
            stopped = st;
        }
        if (!stopped) kar[3] = kal[4];
        idesc[20] = la_[b];
        idesc[21] = vt0;
        int* dd = DESC + b * 32;
        for (int c = 0; c < 26; c++) { dd[c] = idesc[c]; sdesc[tb][c] = idesc[c]; }
        float* oa = out + b * 12;
        for (int c = 0; c < 4; c++) {
            oa[c]     = (float)ai[c];
            oa[4 + c] = (float)kal[c];
            oa[8 + c] = (float)kar[c];
        }
    }
    __syncthreads();

    // ---- phase 1: V, X-prefetch (needs sdesc), q0 (needs hmb) ----
#pragma unroll
    for (int k = 0; k < 8; k++) {
        int o = t + 512 * k;               // 4096 = 16b x 256
        int b = o >> 8, idx = o & 255;
        float a = mb2[idx];
#pragma unroll
        for (int u = 0; u < 8; u++) a += mW2[idx * 8 + u] * hid[b][u];
        F[FI_V + (b0 + b) * 256 + idx] = a;
    }
    for (int e = t; e < 2048; e += 512) {  // step 0: iq broadcast to 16 rows
        int row = e >> 7, d = e & 127;
        Xall[0][row][d] = f2bf(iq[d]);
    }
    for (int e = t; e < 6144; e += 512) {  // steps 1..3 gathered rows
        int i = (e >> 11) + 1;
        int b = (e >> 7) & 15, d = e & 127;
        int a = sdesc[b][i - 1];
        int srcrow = a;
        if (rho) {
            int sE = sdesc[b][16 + (i - 1)];
            int nl = sdesc[b][22 + (i - 1)];
            srcrow = sE ? a : (nl & (GS - 1));
        }
        Xall[i][b][d] = f2bf(h[((size_t)((b0 + b) * GS + srcrow)) * DD + d]);
    }
    // q0 = hm @ ihw^T + ihb (wave w covers n = w*16..w*16+16)
    float qreg[4];
    {
        bf16x8_t am[4];
#pragma unroll
        for (int kt = 0; kt < 4; kt++)
            am[kt] = *(const bf16x8_t*)&hmb[ml][kt * 32 + quad * 8];
        const unsigned short* wb = wihb + (size_t)dloc * 128 + quad * 8;
        f32x4_t acc = {0.f, 0.f, 0.f, 0.f};
#pragma unroll
        for (int kt = 0; kt < 4; kt++)
            acc = MFMA16(am[kt], *(const bf16x8_t*)(wb + kt * 32), acc);
        float bias = ihb[dloc];
#pragma unroll
        for (int r_ = 0; r_ < 4; r_++) {
            qreg[r_] = acc[r_] + bias;
            Qb[0][quad * 4 + r_][dloc] = f2bf(qreg[r_]);
        }
    }
    __syncthreads();

    // ---- phase 2: 4 GRU steps + AQ, one barrier per step ----
    float bir = bih[dloc], biz = bih[128 + dloc], bin_ = bih[256 + dloc];
    float bhr = bhh[dloc], bhz = bhh[128 + dloc], bhn = bhh[256 + dloc];

    for (int i = 0; i < 4; i++) {
        int cur = i & 1;
        bf16x8_t ax[4], aq[4];
#pragma unroll
        for (int kt = 0; kt < 4; kt++) {
            ax[kt] = *(const bf16x8_t*)&Xall[i][ml][kt * 32 + quad * 8];
            aq[kt] = *(const bf16x8_t*)&Qb[cur][ml][kt * 32 + quad * 8];
        }
        f32x4_t gi[3], gh[3];
#pragma unroll
        for (int gate = 0; gate < 3; gate++) {
            int n = gate * 128 + dloc;
            const unsigned short* wi = wgru + ((size_t)((rho * 2 + 0) * 384 + n)) * 128 + quad * 8;
            const unsigned short* wh = wgru + ((size_t)((rho * 2 + 1) * 384 + n)) * 128 + quad * 8;
            f32x4_t ai = {0.f, 0.f, 0.f, 0.f}, ah = {0.f, 0.f, 0.f, 0.f};
#pragma unroll
            for (int kt = 0; kt < 4; kt++) {
                ai = MFMA16(ax[kt], *(const bf16x8_t*)(wi + kt * 32), ai);
                ah = MFMA16(aq[kt], *(const bf16x8_t*)(wh + kt * 32), ah);
            }
            gi[gate] = ai; gh[gate] = ah;
        }
#pragma unroll
        for (int r_ = 0; r_ < 4; r_++) {
            float r = sigm2(gi[0][r_] + bir + gh[0][r_] + bhr);
            float z = sigm2(gi[1][r_] + biz + gh[1][r_] + bhz);
            float n = tanh2(gi[2][r_] + bin_ + r * (gh[2][r_] + bhn));
            qreg[r_] = fmaf(z, qreg[r_] - n, n);
            Qb[cur ^ 1][quad * 4 + r_][dloc] = f2bf(qreg[r_]);
        }
        __syncthreads();

        // AQ projection from q' (reads Qb[cur^1])
        bf16x8_t aqn[4];
#pragma unroll
        for (int kt = 0; kt < 4; kt++)
            aqn[kt] = *(const bf16x8_t*)&Qb[cur ^ 1][ml][kt * 32 + quad * 8];
#pragma unroll
        for (int half = 0; half < 2; half++) {
            int nrow = half * 128 + dloc;
            const unsigned short* wq = wqp + ((size_t)(rho * 256 + nrow)) * 128 + quad * 8;
            f32x4_t acc = {0.f, 0.f, 0.f, 0.f};
#pragma unroll
            for (int kt = 0; kt < 4; kt++)
                acc = MFMA16(aqn[kt], *(const bf16x8_t*)(wq + kt * 32), acc);
            int sel = rho * 2 + half;
#pragma unroll
            for (int r_ = 0; r_ < 4; r_++) {
                int b2 = b0 + quad * 4 + r_;
                F[FJ_AQB + b2 * 2048 + dloc * 16 + i * 4 + sel] = acc[r_];
            }
        }
    }
}

// ---------------- kernel C: barrier-free score, 256-thr half-d blocks -------
// grid 2048 = (b, gq 0..3, half 0..1); 256 thr = 4 waves.
// launch_bounds(256,4): 128-reg budget -> 4 blocks/CU (16 waves). Single
// A-buffer; next-tile load issued between MFMA phase and VALU epilogue so
// its latency hides under the ~340cy epilogue. Per-r butterfly keeps live
// range small. bfr NOT pinned: under pressure the compiler rematerializes
// cold fragments from L1 (cheap) instead of scratch-spilling.
#define LOADA(dst, TL) do {                                                    \
    if (HBF) {                                                                 \
        _Pragma("unroll")                                                      \
        for (int kt = 0; kt < 4; kt++)                                         \
            dst[kt] = *(const bf16x8_t*)(ab + (size_t)(TL) * 2048 + kt * 512); \
    } else {                                                                   \
        _Pragma("unroll")                                                      \
        for (int kt = 0; kt < 4; kt++) {                                       \
            f32x4_t lo = *(const f32x4_t*)(fb + (size_t)(TL) * 2048 + kt * 32);     \
            f32x4_t hi = *(const f32x4_t*)(fb + (size_t)(TL) * 2048 + kt * 32 + 4); \
            union { unsigned short s[8]; bf16x8_t v; } pk_;                    \
            pk_.s[0] = f2bf(lo[0]); pk_.s[1] = f2bf(lo[1]);                    \
            pk_.s[2] = f2bf(lo[2]); pk_.s[3] = f2bf(lo[3]);                    \
            pk_.s[4] = f2bf(hi[0]); pk_.s[5] = f2bf(hi[1]);                    \
            pk_.s[6] = f2bf(hi[2]); pk_.s[7] = f2bf(hi[3]);                    \
            dst[kt] = pk_.v;                                                   \
        }                                                                      \
    }                                                                          \
} while (0)

#define MFMA_PHASE(af) do {                                                    \
    _Pragma("unroll") for (int m_ = 0; m_ < 4; m_++)                           \
        c[m_] = (f32x4_t){0.f, 0.f, 0.f, 0.f};                                 \
    _Pragma("unroll") for (int kt = 0; kt < 4; kt++) {                         \
        _Pragma("unroll") for (int m_ = 0; m_ < 4; m_++)                       \
            c[m_] = MFMA16(af[kt], bfr[m_][kt], c[m_]);                        \
    }                                                                          \
} while (0)

// per-r epilogue + butterfly; exact same lane algebra as the verified
// 16-slot butterfly (slot i=ml => r=ml>>2, j=ml&3), restructured to shrink
// live range: levels 1-2 inside the r-loop, levels 3-4 after.
#define EPILOGUE(TL) do {                                                      \
    float w0_, w1_, w2_, w3_;                                                  \
    _Pragma("unroll") for (int r_ = 0; r_ < 4; r_++) {                         \
        f32x2_t cA = {c[0][r_], c[1][r_]};                                     \
        f32x2_t cM = {c[2][r_], c[3][r_]};                                     \
        float u_[4];                                                           \
        _Pragma("unroll") for (int j_ = 0; j_ < 4; j_++) {                     \
            f32x2_t y = cA + aa[j_] + cM * bb[j_];                             \
            f32x2_t s = y * y + (f32x2_t){1.0f, 1.0f};                         \
            f32x2_t rs = {__builtin_amdgcn_rsqf(s[0]), __builtin_amdgcn_rsqf(s[1])}; \
            f32x2_t tv = y * rs * VV;                                          \
            u_[j_] = tv[0] + tv[1];                                            \
        }                                                                      \
        float p0_, p1_;                                                        \
        { int bs = ml & 1;                                                     \
          p0_ = (bs ? u_[1] : u_[0]) + __shfl_xor(bs ? u_[0] : u_[1], 1);      \
          p1_ = (bs ? u_[3] : u_[2]) + __shfl_xor(bs ? u_[2] : u_[3], 1); }    \
        float wr_;                                                             \
        { int bs = (ml >> 1) & 1;                                              \
          wr_ = (bs ? p1_ : p0_) + __shfl_xor(bs ? p0_ : p1_, 2); }            \
        if (r_ == 0) w0_ = wr_; else if (r_ == 1) w1_ = wr_;                   \
        else if (r_ == 2) w2_ = wr_; else w3_ = wr_;                           \
    }                                                                          \
    float q0_, q1_, v0_;                                                       \
    { int bs = (ml >> 2) & 1;                                                  \
      q0_ = (bs ? w1_ : w0_) + __shfl_xor(bs ? w0_ : w1_, 4);                  \
      q1_ = (bs ? w3_ : w2_) + __shfl_xor(bs ? w2_ : w3_, 4); }                \
    { int bs = (ml >> 3) & 1;                                                  \
      v0_ = (bs ? q1_ : q0_) + __shfl_xor(bs ? q0_ : q1_, 8); }                \
    atomicAdd(&red[TL][quad * 16 + ml], v0_);                                  \
} while (0)

template<int HBF>
__global__ __launch_bounds__(256, 4) void score_kernel(
    const float* __restrict__ h, const unsigned short* __restrict__ hbw,
    const unsigned short* __restrict__ wbf, float* __restrict__ F)
{
    int bid = blockIdx.x;
    int half = bid & 1, gq = (bid >> 1) & 3, b = bid >> 3;
    int t = threadIdx.x;
    int lane = t & 63, w = t >> 6;          // w 0..3
    int ml = lane & 15, quad = lane >> 4;
    int dg = half * 64 + w * 16 + ml;       // this lane's output-d column

    __shared__ float red[16][64];           // per-tile (g,j) partial sums
    for (int e = t; e < 1024; e += 256) ((float*)red)[e] = 0.0f;

    // per-lane B-fragments (loop-invariant; compiler may remat from L1)
    bf16x8_t bfr[4][4];
#pragma unroll
    for (int mat = 0; mat < 4; mat++)
#pragma unroll
        for (int kt = 0; kt < 4; kt++)
            bfr[mat][kt] = *(const bf16x8_t*)(wbf + ((size_t)(mat * 128 + dg)) * 128 + kt * 32 + quad * 8);

    const float* Vb = F + FI_V + b * 256;
    f32x2_t VV = {Vb[dg], Vb[128 + dg]};
    const float* AQ = F + FJ_AQB + b * 2048 + dg * 16;
    f32x2_t aa[4], bb[4];
#pragma unroll
    for (int j = 0; j < 4; j++) {
        f32x4_t q = *(const f32x4_t*)(AQ + j * 4);   // {a1,b1,a2,b2}
        aa[j] = (f32x2_t){q[0], q[2]};
        bb[j] = (f32x2_t){q[1], q[3]};
    }

    __syncthreads();   // red zero-init visible to all waves

    int grow0 = gq * 256;
    // swizzled per-lane A source: tile base + lane*16B (coalesced)
    const unsigned short* ab = hbw + ((size_t)(b * 64 + gq * 16)) * 2048 + (size_t)lane * 8;
    // fallback f32 source (row = ml, k-chunk = kt*32+quad*8)
    const float*          fb = h   + ((size_t)(b * GS + grow0) + ml) * 128 + quad * 8;

    bf16x8_t afA[4];
    LOADA(afA, 0);
#pragma unroll
    for (int tl = 0; tl < 16; tl++) {
        f32x4_t c[4];
        MFMA_PHASE(afA);
        if (tl < 15) LOADA(afA, tl + 1);   // latency hides under epilogue
        EPILOGUE(tl);
    }
    __syncthreads();

    // drain: atomic accumulate this half's partials into FK_RES
    for (int e = t; e < 1024; e += 256) {
        int j = e >> 8, gl = e & 255;
        int tl = gl >> 4, row = gl & 15;
        float val = red[tl][(row >> 2) * 16 + (row & 3) * 4 + j];
        atomicAdd(&F[FK_RES + (size_t)b * 4096 + j * 1024 + grow0 + gl], val);
    }
}

// ---------------- kernel D: masked log-softmax + ll, (b,j) split ------------
// grid 1024 = (b, j); gated j-blocks exit immediately; each block computes
// its j's lse + chosen and atomicAdds into out[3072+b] (zeroed by prep).
__global__ __launch_bounds__(256) void finalize_kernel(
    const float* __restrict__ F, const int* __restrict__ DESC,
    const int* __restrict__ vt, float* __restrict__ out)
{
    int bj = blockIdx.x;
    int b = bj >> 2, j = bj & 3;
    const int* dd = DESC + b * 32;
    if (j > 0 && dd[16 + j]) return;        // gated: zero contribution
    int t = threadIdx.x;
    int act0 = dd[0], la = dd[20], vt0 = dd[21];
    __shared__ float sred[8];
    __shared__ float schosen;

    int aj = dd[j];
    float lg[4];
#pragma unroll
    for (int q = 0; q < 4; q++) {
        int g = t + q * 256;
        bool neg;
        if (j == 0) {
            neg = (g == la);
        } else {
            int p = j - 1;
            int vtt = (vt[b * GS + g] - vt0) & (GS - 1);
            neg = (vtt <= dd[4 + p]) || (p == 0 && vtt > GS - 2);
            if (dd[8 + p] && g == dd[p]) neg = false;
            if (dd[12 + p] && g == act0) neg = false;
        }
        float r = F[FK_RES + (size_t)b * 4096 + j * 1024 + g];
        float vv = neg ? NEGV : 6.0f * rtanh(r);
        lg[q] = vv;
        if (g == aj) schosen = vv;
    }
    float mx = fmaxf(fmaxf(lg[0], lg[1]), fmaxf(lg[2], lg[3]));
#pragma unroll
    for (int o = 1; o < 64; o <<= 1) mx = fmaxf(mx, __shfl_xor(mx, o));
    if ((t & 63) == 0) sred[t >> 6] = mx;
    __syncthreads();
    mx = fmaxf(fmaxf(sred[0], sred[1]), fmaxf(sred[2], sred[3]));
    float sm = 0.0f;
#pragma unroll
    for (int q = 0; q < 4; q++) sm += __expf(lg[q] - mx);
#pragma unroll
    for (int o = 1; o < 64; o <<= 1) sm += __shfl_xor(sm, o);
    if ((t & 63) == 0) sred[4 + (t >> 6)] = sm;
    __syncthreads();
    if (t == 0) {
        float tot = sred[4] + sred[5] + sred[6] + sred[7];
        float lse = mx + logf(tot);
        atomicAdd(&out[3072 + b], schosen - lse);
    }
}

extern "C" void kernel_launch(void* const* d_in, const int* in_sizes, int n_in,
                              void* d_out, int out_size, void* d_ws, size_t ws_size,
                              hipStream_t stream)
{
    (void)in_sizes; (void)n_in; (void)out_size;
    const float* h    = (const float*)d_in[0];
    const float* ctx2 = (const float*)d_in[1];
    const int*   rec  = (const int*)d_in[2];
    const int*   vtm  = (const int*)d_in[3];
    const int*   la   = (const int*)d_in[4];
    const int*   fa   = (const int*)d_in[5];
    const float* wk1 = (const float*)d_in[7];
    const float* wk2 = (const float*)d_in[8];
    const float* wk3 = (const float*)d_in[9];
    const float* wk4 = (const float*)d_in[10];
    const float* wq1 = (const float*)d_in[11];
    const float* wq2 = (const float*)d_in[12];
    const float* wq3 = (const float*)d_in[13];
    const float* wq4 = (const float*)d_in[14];
    const float* mW1 = (const float*)d_in[15];
    const float* mb1 = (const float*)d_in[16];
    const float* mW2 = (const float*)d_in[17];
    const float* mb2 = (const float*)d_in[18];
    const float* ihw = (const float*)d_in[19];
    const float* ihb = (const float*)d_in[20];
    const float* iq  = (const float*)d_in[21];
    const float* r1ih = (const float*)d_in[22];
    const float* r1hh = (const float*)d_in[23];
    const float* b1ih = (const float*)d_in[24];
    const float* b1hh = (const float*)d_in[25];
    const float* r2ih = (const float*)d_in[26];
    const float* r2hh = (const float*)d_in[27];
    const float* b2ih = (const float*)d_in[28];
    const float* b2hh = (const float*)d_in[29];

    unsigned short* wbf  = (unsigned short*)d_ws;
    unsigned short* wgru = (unsigned short*)((char*)d_ws + WGRU_OFF_BYTES);
    unsigned short* wqp  = (unsigned short*)((char*)d_ws + WQP_OFF_BYTES);
    unsigned short* wihb = (unsigned short*)((char*)d_ws + WIHB_OFF_BYTES);
    float* F   = (float*)((char*)d_ws + F_OFF_BYTES);
    int* DESC  = (int*)((char*)d_ws + DESC_OFF_BYTES);
    unsigned short* hbw = (unsigned short*)((char*)d_ws + HBF_OFF_BYTES);
    float* out = (float*)d_out;

    int use_hbf = (ws_size >= WS_NEED) ? 1 : 0;

    init_kernel<<<dim3(2176), dim3(128), 0, stream>>>(h, wk1, wk2, wk3, wk4,
                                                      wq1, wq2, wq3, wq4, ihw,
                                                      r1ih, r1hh, r2ih, r2hh,
                                                      wbf, wgru, wqp, wihb, F,
                                                      hbw, use_hbf);
    prep_kernel<<<dim3(32), dim3(512), 0, stream>>>(h, ctx2, rec, vtm, la, fa,
                                                    mW1, mb1, mW2, mb2, ihb, iq,
                                                    b1ih, b1hh, b2ih, b2hh,
                                                    wgru, wqp, wihb, F, DESC, out);
    if (use_hbf)
        score_kernel<1><<<dim3(2048), dim3(256), 0, stream>>>(h, hbw, wbf, F);
    else
        score_kernel<0><<<dim3(2048), dim3(256), 0, stream>>>(h, hbw, wbf, F);
    finalize_kernel<<<dim3(1024), dim3(256), 0, stream>>>(F, DESC, vtm, out);
}

// Round 8
// 410.485 us; speedup vs baseline: 1.0763x; 1.0763x over previous
//
#include <hip/hip_runtime.h>
#include <hip/hip_bf16.h>
#include <math.h>

#define GS 1024
#define BSZ 256
#define DD 128
#define NEGV -1e30f

typedef __attribute__((ext_vector_type(8))) short bf16x8_t;
typedef __attribute__((ext_vector_type(4))) float f32x4_t;
typedef __attribute__((ext_vector_type(2))) float f32x2_t;

// ---- workspace layout (bytes) ---- (identical to proven 405us layout)
#define WGRU_OFF_BYTES 131072
#define WQP_OFF_BYTES  524288
#define WIHB_OFF_BYTES 655360
#define F_OFF_BYTES    688128
// float offsets inside F:
#define FH_HM   0        // 262144  h-mean partials [b][seg][d]
#define FI_V    262144   // 65536   [b][256] V1|V2
#define FJ_AQB  327680   // 524288  [b][d][j][sel]  sel = {a1,b1,a2,b2}
#define FK_RES  851968   // 1048576 [b][j][g]  (fallback path only)
#define F_TOTAL 1900544
#define DESC_OFF_BYTES (F_OFF_BYTES + F_TOTAL * 4)   // int [b][32]
// optional regions (only touched when ws_size >= WS_NEED):
// bf16 h image, MFMA-fragment-swizzled:
//   hbw[(((b*64 + T)*4 + kt)*64 + lane)*8 + j] = h[b][T*16 + (lane&15)][kt*32 + (lane>>4)*8 + j]
#define HBF_OFF_BYTES  (DESC_OFF_BYTES + 32768)      // 64 MB
#define FK2_OFF_BYTES  (HBF_OFF_BYTES + (size_t)BSZ * GS * DD * 2)  // 2x 4MB half-d partials
#define WS_NEED (FK2_OFF_BYTES + (size_t)2 * 1048576 * 4)

__device__ __forceinline__ float rtanh(float x) {
    float s = fmaf(x, x, 1.0f);
    return x * __builtin_amdgcn_rsqf(s);
}
__device__ __forceinline__ float tanh2(float x) {
    float e = __expf(x + x);
    return fmaf(-2.0f, __builtin_amdgcn_rcpf(e + 1.0f), 1.0f);
}
__device__ __forceinline__ float sigm2(float x) {
    return __builtin_amdgcn_rcpf(1.0f + __expf(-x));
}
__device__ __forceinline__ unsigned short f2bf(float f) {
    union { float f; unsigned u; } v; v.f = f;
    unsigned u = v.u;
    return (unsigned short)((u + 0x7fffu + ((u >> 16) & 1u)) >> 16);
}
#define MFMA16(a, b, c) __builtin_amdgcn_mfma_f32_16x16x32_bf16((a), (b), (c), 0, 0, 0)

// ---------------- kernel A: fused hmean (+ gated swizzled h->bf16) + pack ----
__global__ __launch_bounds__(128) void init_kernel(
    const float* __restrict__ h,
    const float* __restrict__ wk1, const float* __restrict__ wk2,
    const float* __restrict__ wk3, const float* __restrict__ wk4,
    const float* __restrict__ wq1, const float* __restrict__ wq2,
    const float* __restrict__ wq3, const float* __restrict__ wq4,
    const float* __restrict__ ihw,
    const float* __restrict__ r1ih, const float* __restrict__ r1hh,
    const float* __restrict__ r2ih, const float* __restrict__ r2hh,
    unsigned short* __restrict__ wbf, unsigned short* __restrict__ wgru,
    unsigned short* __restrict__ wqp, unsigned short* __restrict__ wihb,
    float* __restrict__ F, unsigned short* __restrict__ hbw, int use_hbf)
{
    if (blockIdx.x < 2048) {
        int b = blockIdx.x >> 3, seg = blockIdx.x & 7;
        int t = threadIdx.x;
        int rg = t >> 4, c = t & 15;
        int kt = c >> 2, quad = c & 3;
        // skewed LDS image: chunk q (16B) lives at byte (q + (q>>4)) * 16
        __shared__ __attribute__((aligned(16))) unsigned short lim[17408]; // 34816 B
        __shared__ float cs[8][128];
        float s0=0.f,s1=0.f,s2=0.f,s3=0.f,s4=0.f,s5=0.f,s6=0.f,s7=0.f;
#pragma unroll
        for (int i = 0; i < 16; i++) {
            int rl = rg + 8 * i;
            const float* src = h + ((size_t)(b * GS + seg * 128 + rl)) * DD + c * 8;
            f32x4_t lo = *(const f32x4_t*)src;
            f32x4_t hi = *(const f32x4_t*)(src + 4);
            s0 += lo[0]; s1 += lo[1]; s2 += lo[2]; s3 += lo[3];
            s4 += hi[0]; s5 += hi[1]; s6 += hi[2]; s7 += hi[3];
            if (use_hbf) {
                int tt = rl >> 4, ml = rl & 15;
                union { unsigned short s[8]; bf16x8_t v; } pk;
                pk.s[0] = f2bf(lo[0]); pk.s[1] = f2bf(lo[1]);
                pk.s[2] = f2bf(lo[2]); pk.s[3] = f2bf(lo[3]);
                pk.s[4] = f2bf(hi[0]); pk.s[5] = f2bf(hi[1]);
                pk.s[6] = f2bf(hi[2]); pk.s[7] = f2bf(hi[3]);
                int q = tt * 256 + kt * 64 + quad * 16 + ml;   // local chunk idx
                int ob16 = q + (q >> 4);                        // skew: +16B per 256B
                *(bf16x8_t*)&lim[ob16 * 8] = pk.v;
            }
        }
        cs[rg][c * 8 + 0] = s0; cs[rg][c * 8 + 1] = s1;
        cs[rg][c * 8 + 2] = s2; cs[rg][c * 8 + 3] = s3;
        cs[rg][c * 8 + 4] = s4; cs[rg][c * 8 + 5] = s5;
        cs[rg][c * 8 + 6] = s6; cs[rg][c * 8 + 7] = s7;
        __syncthreads();
        {
            int d = t;
            float s = 0.0f;
#pragma unroll
            for (int k = 0; k < 8; k++) s += cs[k][d];
            F[FH_HM + b * 1024 + seg * 128 + d] = s;
        }
        if (use_hbf) {
            unsigned short* dst = hbw + ((size_t)(b * 64 + seg * 8)) * 2048;
#pragma unroll
            for (int it = 0; it < 16; it++) {
                int e = it * 128 + t;
                int ob16 = e + (e >> 4);
                bf16x8_t v = *(const bf16x8_t*)&lim[ob16 * 8];
                *(bf16x8_t*)(dst + (size_t)e * 8) = v;   // linear, coalesced
            }
        }
        return;
    }
    int tid = (blockIdx.x - 2048) * 128 + threadIdx.x;
    int nth = 128 * 128;
    const float* wks[4]  = {wk1, wk2, wk3, wk4};
    const float* rws[4]  = {r1ih, r1hh, r2ih, r2hh};
    const float* wqs2[4] = {wq1, wq3, wq2, wq4};

    for (int e = tid; e < 65536; e += nth)            // W_K bf16 [mat][d][k]
        wbf[e] = f2bf(wks[e >> 14][e & 16383]);
    for (int e = tid; e < 196608; e += nth)           // GRU weights row-major
        wgru[e] = f2bf(rws[e / 49152][e % 49152]);
    for (int e = tid; e < 65536; e += nth)            // WQ pairs row-major
        wqp[e] = f2bf(wqs2[e >> 14][e & 16383]);
    for (int e = tid; e < 16384; e += nth)            // init_hidden_W row-major [d][k]
        wihb[e] = f2bf(ihw[e]);
    if (!use_hbf)
        for (int e = tid; e < 1048576; e += nth)      // zero FK_RES (fallback atomics)
            F[FK_RES + e] = 0.0f;
}

// ---------------- kernel B: fused prep + 4 GRU steps + AQ (proven version) ---
__global__ __launch_bounds__(512) void prep_kernel(
    const float* __restrict__ h, const float* __restrict__ ctx2,
    const int* __restrict__ rec, const int* __restrict__ vt,
    const int* __restrict__ la_, const int* __restrict__ fa,
    const float* __restrict__ mW1, const float* __restrict__ mb1,
    const float* __restrict__ mW2, const float* __restrict__ mb2,
    const float* __restrict__ ihb, const float* __restrict__ iq,
    const float* __restrict__ b1ih, const float* __restrict__ b1hh,
    const float* __restrict__ b2ih, const float* __restrict__ b2hh,
    const unsigned short* __restrict__ wgru, const unsigned short* __restrict__ wqp,
    const unsigned short* __restrict__ wihb,
    float* __restrict__ F, int* __restrict__ DESC, float* __restrict__ out)
{
    int rho = blockIdx.x & 1;
    int b0  = (blockIdx.x >> 1) * 16;
    int t = threadIdx.x;
    int lane = t & 63, w = t >> 6, ml = lane & 15, quad = lane >> 4;
    int dloc = w * 16 + ml;     // this lane's d

    __shared__ __attribute__((aligned(16))) unsigned short hmb[16][136];
    __shared__ __attribute__((aligned(16))) unsigned short Xall[4][16][136];
    __shared__ __attribute__((aligned(16))) unsigned short Qb[2][16][136];
    __shared__ float hid[16][8];
    __shared__ int sdesc[16][26];

    const float* bih = rho ? b2ih : b1ih;
    const float* bhh = rho ? b2hh : b1hh;

    // ---- phase 0: hm sums, meta hidden, int machine (independent) ----
#pragma unroll
    for (int k = 0; k < 4; k++) {
        int e = t + 512 * k;               // 2048 = 16b x 128d
        int b = e >> 7, d = e & 127;
        float s = 0.0f;
#pragma unroll
        for (int seg = 0; seg < 8; seg++)
            s += F[FH_HM + (b0 + b) * 1024 + seg * 128 + d];
        hmb[b][d] = f2bf(s * (1.0f / 1024.0f));
    }
    if (t < 128) {
        int b = t >> 3, u = t & 7;
        float a = mb1[u];
        for (int k = 0; k < 9; k++) a += mW1[u * 9 + k] * ctx2[(b0 + b) * 9 + k];
        hid[b][u] = a > 0.0f ? a : 0.0f;
    }
    if (rho == 0 && t >= 144 && t < 160)    // zero ll accumulators for finalize
        out[3072 + b0 + (t - 144)] = 0.0f;
    if (t >= 128 && t < 144) {
        int tb = t - 128;
        int b = b0 + tb;
        int ai[4], kal[5] = {0, 0, 0, 0, 0}, kar[4] = {0, 0, 0, 0};
        int idesc[26];
        int stopped = 1, nola = -1, vt0 = 0;
        for (int i = 0; i < 4; i++) {
            idesc[16 + i] = stopped;
            idesc[22 + i] = nola;
            int action = fa[b * 4 + i];
            if (i > 0 && stopped) action = ai[0];
            int nona = rec[b * GS + action];
            ai[i] = action;
            if (stopped) kal[i] = action;
            int jprev = (i + 3) & 3;
            if (!stopped) kar[jprev] = action;
            kal[i + 1] = nona;
            int hit = (action == nola) ? 1 : 0;
            int st = (i > 0) ? (stopped | hit) : hit;
            if (st) kal[i] = kal[(i + 4) % 5];
            if (st) kar[i] = kar[jprev];
            if (i == 0) vt0 = vt[b * GS + action];
            idesc[0 + i]  = action;
            idesc[4 + i]  = (vt[b * GS + action] - vt0) & (GS - 1);
            idesc[8 + i]  = st;
            idesc[12 + i] = (!st && (nona == ai[0])) ? 1 : 0;
            nola = st ? -1 : nona;
            stopped = st;
        }
        if (!stopped) kar[3] = kal[4];
        idesc[20] = la_[b];
        idesc[21] = vt0;
        int* dd = DESC + b * 32;
        for (int c = 0; c < 26; c++) { dd[c] = idesc[c]; sdesc[tb][c] = idesc[c]; }
        float* oa = out + b * 12;
        for (int c = 0; c < 4; c++) {
            oa[c]     = (float)ai[c];
            oa[4 + c] = (float)kal[c];
            oa[8 + c] = (float)kar[c];
        }
    }
    __syncthreads();

    // ---- phase 1: V, X-prefetch (needs sdesc), q0 (needs hmb) ----
#pragma unroll
    for (int k = 0; k < 8; k++) {
        int o = t + 512 * k;               // 4096 = 16b x 256
        int b = o >> 8, idx = o & 255;
        float a = mb2[idx];
#pragma unroll
        for (int u = 0; u < 8; u++) a += mW2[idx * 8 + u] * hid[b][u];
        F[FI_V + (b0 + b) * 256 + idx] = a;
    }
    for (int e = t; e < 2048; e += 512) {  // step 0: iq broadcast to 16 rows
        int row = e >> 7, d = e & 127;
        Xall[0][row][d] = f2bf(iq[d]);
    }
    for (int e = t; e < 6144; e += 512) {  // steps 1..3 gathered rows
        int i = (e >> 11) + 1;
        int b = (e >> 7) & 15, d = e & 127;
        int a = sdesc[b][i - 1];
        int srcrow = a;
        if (rho) {
            int sE = sdesc[b][16 + (i - 1)];
            int nl = sdesc[b][22 + (i - 1)];
            srcrow = sE ? a : (nl & (GS - 1));
        }
        Xall[i][b][d] = f2bf(h[((size_t)((b0 + b) * GS + srcrow)) * DD + d]);
    }
    // q0 = hm @ ihw^T + ihb (wave w covers n = w*16..w*16+16)
    float qreg[4];
    {
        bf16x8_t am[4];
#pragma unroll
        for (int kt = 0; kt < 4; kt++)
            am[kt] = *(const bf16x8_t*)&hmb[ml][kt * 32 + quad * 8];
        const unsigned short* wb = wihb + (size_t)dloc * 128 + quad * 8;
        f32x4_t acc = {0.f, 0.f, 0.f, 0.f};
#pragma unroll
        for (int kt = 0; kt < 4; kt++)
            acc = MFMA16(am[kt], *(const bf16x8_t*)(wb + kt * 32), acc);
        float bias = ihb[dloc];
#pragma unroll
        for (int r_ = 0; r_ < 4; r_++) {
            qreg[r_] = acc[r_] + bias;
            Qb[0][quad * 4 + r_][dloc] = f2bf(qreg[r_]);
        }
    }
    __syncthreads();

    // ---- phase 2: 4 GRU steps + AQ, one barrier per step ----
    float bir = bih[dloc], biz = bih[128 + dloc], bin_ = bih[256 + dloc];
    float bhr = bhh[dloc], bhz = bhh[128 + dloc], bhn = bhh[256 + dloc];

    for (int i = 0; i < 4; i++) {
        int cur = i & 1;
        bf16x8_t ax[4], aq[4];
#pragma unroll
        for (int kt = 0; kt < 4; kt++) {
            ax[kt] = *(const bf16x8_t*)&Xall[i][ml][kt * 32 + quad * 8];
            aq[kt] = *(const bf16x8_t*)&Qb[cur][ml][kt * 32 + quad * 8];
        }
        f32x4_t gi[3], gh[3];
#pragma unroll
        for (int gate = 0; gate < 3; gate++) {
            int n = gate * 128 + dloc;
            const unsigned short* wi = wgru + ((size_t)((rho * 2 + 0) * 384 + n)) * 128 + quad * 8;
            const unsigned short* wh = wgru + ((size_t)((rho * 2 + 1) * 384 + n)) * 128 + quad * 8;
            f32x4_t ai = {0.f, 0.f, 0.f, 0.f}, ah = {0.f, 0.f, 0.f, 0.f};
#pragma unroll
            for (int kt = 0; kt < 4; kt++) {
                ai = MFMA16(ax[kt], *(const bf16x8_t*)(wi + kt * 32), ai);
                ah = MFMA16(aq[kt], *(const bf16x8_t*)(wh + kt * 32), ah);
            }
            gi[gate] = ai; gh[gate] = ah;
        }
#pragma unroll
        for (int r_ = 0; r_ < 4; r_++) {
            float r = sigm2(gi[0][r_] + bir + gh[0][r_] + bhr);
            float z = sigm2(gi[1][r_] + biz + gh[1][r_] + bhz);
            float n = tanh2(gi[2][r_] + bin_ + r * (gh[2][r_] + bhn));
            qreg[r_] = fmaf(z, qreg[r_] - n, n);
            Qb[cur ^ 1][quad * 4 + r_][dloc] = f2bf(qreg[r_]);
        }
        __syncthreads();

        // AQ projection from q' (reads Qb[cur^1])
        bf16x8_t aqn[4];
#pragma unroll
        for (int kt = 0; kt < 4; kt++)
            aqn[kt] = *(const bf16x8_t*)&Qb[cur ^ 1][ml][kt * 32 + quad * 8];
#pragma unroll
        for (int half = 0; half < 2; half++) {
            int nrow = half * 128 + dloc;
            const unsigned short* wq = wqp + ((size_t)(rho * 256 + nrow)) * 128 + quad * 8;
            f32x4_t acc = {0.f, 0.f, 0.f, 0.f};
#pragma unroll
            for (int kt = 0; kt < 4; kt++)
                acc = MFMA16(aqn[kt], *(const bf16x8_t*)(wq + kt * 32), acc);
            int sel = rho * 2 + half;
#pragma unroll
            for (int r_ = 0; r_ < 4; r_++) {
                int b2 = b0 + quad * 4 + r_;
                F[FJ_AQB + b2 * 2048 + dloc * 16 + i * 4 + sel] = acc[r_];
            }
        }
    }
}

// ---------------- kernel C: barrier-free score, 256-thr half-d blocks -------
// grid 2048 = (b, gq 0..3, half 0..1); 256 thr = 4 waves.
// launch_bounds(256,4): 128-reg budget. bfr PINNED (R3/R4: pin keeps the 64
// frag regs resident in the unified file, no scratch). Single A-buffer,
// next-tile load AFTER the epilogue (no 2nd buffer live through it).
// HBF=1: drain = plain stores to FK2 half-d partials (no atomics).
#define LOADA(dst, TL) do {                                                    \
    if (HBF) {                                                                 \
        _Pragma("unroll")                                                      \
        for (int kt = 0; kt < 4; kt++)                                         \
            dst[kt] = *(const bf16x8_t*)(ab + (size_t)(TL) * 2048 + kt * 512); \
    } else {                                                                   \
        _Pragma("unroll")                                                      \
        for (int kt = 0; kt < 4; kt++) {                                       \
            f32x4_t lo = *(const f32x4_t*)(fb + (size_t)(TL) * 2048 + kt * 32);     \
            f32x4_t hi = *(const f32x4_t*)(fb + (size_t)(TL) * 2048 + kt * 32 + 4); \
            union { unsigned short s[8]; bf16x8_t v; } pk_;                    \
            pk_.s[0] = f2bf(lo[0]); pk_.s[1] = f2bf(lo[1]);                    \
            pk_.s[2] = f2bf(lo[2]); pk_.s[3] = f2bf(lo[3]);                    \
            pk_.s[4] = f2bf(hi[0]); pk_.s[5] = f2bf(hi[1]);                    \
            pk_.s[6] = f2bf(hi[2]); pk_.s[7] = f2bf(hi[3]);                    \
            dst[kt] = pk_.v;                                                   \
        }                                                                      \
    }                                                                          \
} while (0)

#define MFMA_PHASE(af) do {                                                    \
    _Pragma("unroll") for (int m_ = 0; m_ < 4; m_++)                           \
        c[m_] = (f32x4_t){0.f, 0.f, 0.f, 0.f};                                 \
    _Pragma("unroll") for (int kt = 0; kt < 4; kt++) {                         \
        _Pragma("unroll") for (int m_ = 0; m_ < 4; m_++)                       \
            c[m_] = MFMA16(af[kt], bfr[m_][kt], c[m_]);                        \
    }                                                                          \
} while (0)

// per-r epilogue + butterfly; same lane algebra as the verified 16-slot
// butterfly (slot i=ml => r=ml>>2, j=ml&3); levels 1-2 inside the r-loop.
#define EPILOGUE(TL) do {                                                      \
    float w0_, w1_, w2_, w3_;                                                  \
    _Pragma("unroll") for (int r_ = 0; r_ < 4; r_++) {                         \
        f32x2_t cA = {c[0][r_], c[1][r_]};                                     \
        f32x2_t cM = {c[2][r_], c[3][r_]};                                     \
        float u_[4];                                                           \
        _Pragma("unroll") for (int j_ = 0; j_ < 4; j_++) {                     \
            f32x2_t y = cA + aa[j_] + cM * bb[j_];                             \
            f32x2_t s = y * y + (f32x2_t){1.0f, 1.0f};                         \
            f32x2_t rs = {__builtin_amdgcn_rsqf(s[0]), __builtin_amdgcn_rsqf(s[1])}; \
            f32x2_t tv = y * rs * VV;                                          \
            u_[j_] = tv[0] + tv[1];                                            \
        }                                                                      \
        float p0_, p1_;                                                        \
        { int bs = ml & 1;                                                     \
          p0_ = (bs ? u_[1] : u_[0]) + __shfl_xor(bs ? u_[0] : u_[1], 1);      \
          p1_ = (bs ? u_[3] : u_[2]) + __shfl_xor(bs ? u_[2] : u_[3], 1); }    \
        float wr_;                                                             \
        { int bs = (ml >> 1) & 1;                                              \
          wr_ = (bs ? p1_ : p0_) + __shfl_xor(bs ? p0_ : p1_, 2); }            \
        if (r_ == 0) w0_ = wr_; else if (r_ == 1) w1_ = wr_;                   \
        else if (r_ == 2) w2_ = wr_; else w3_ = wr_;                           \
    }                                                                          \
    float q0_, q1_, v0_;                                                       \
    { int bs = (ml >> 2) & 1;                                                  \
      q0_ = (bs ? w1_ : w0_) + __shfl_xor(bs ? w0_ : w1_, 4);                  \
      q1_ = (bs ? w3_ : w2_) + __shfl_xor(bs ? w2_ : w3_, 4); }                \
    { int bs = (ml >> 3) & 1;                                                  \
      v0_ = (bs ? q1_ : q0_) + __shfl_xor(bs ? q0_ : q1_, 8); }                \
    atomicAdd(&red[TL][quad * 16 + ml], v0_);                                  \
} while (0)

template<int HBF>
__global__ __launch_bounds__(256, 4) void score_kernel(
    const float* __restrict__ h, const unsigned short* __restrict__ hbw,
    const unsigned short* __restrict__ wbf, float* __restrict__ F,
    float* __restrict__ FK2)
{
    int bid = blockIdx.x;
    int half = bid & 1, gq = (bid >> 1) & 3, b = bid >> 3;
    int t = threadIdx.x;
    int lane = t & 63, w = t >> 6;          // w 0..3
    int ml = lane & 15, quad = lane >> 4;
    int dg = half * 64 + w * 16 + ml;       // this lane's output-d column

    __shared__ float red[16][64];           // per-tile (g,j) partial sums
    for (int e = t; e < 1024; e += 256) ((float*)red)[e] = 0.0f;

    // persistent per-lane B-fragments, pinned (R3/R4 evidence: keeps them
    // resident in the unified file instead of scratch)
    bf16x8_t bfr[4][4];
#pragma unroll
    for (int mat = 0; mat < 4; mat++)
#pragma unroll
        for (int kt = 0; kt < 4; kt++)
            bfr[mat][kt] = *(const bf16x8_t*)(wbf + ((size_t)(mat * 128 + dg)) * 128 + kt * 32 + quad * 8);
#pragma unroll
    for (int mat = 0; mat < 4; mat++)
#pragma unroll
        for (int kt = 0; kt < 4; kt++)
            asm volatile("" : "+v"(bfr[mat][kt]));

    const float* Vb = F + FI_V + b * 256;
    f32x2_t VV = {Vb[dg], Vb[128 + dg]};
    const float* AQ = F + FJ_AQB + b * 2048 + dg * 16;
    f32x2_t aa[4], bb[4];
#pragma unroll
    for (int j = 0; j < 4; j++) {
        f32x4_t q = *(const f32x4_t*)(AQ + j * 4);   // {a1,b1,a2,b2}
        aa[j] = (f32x2_t){q[0], q[2]};
        bb[j] = (f32x2_t){q[1], q[3]};
    }

    __syncthreads();   // red zero-init visible to all waves

    int grow0 = gq * 256;
    // swizzled per-lane A source: tile base + lane*16B (coalesced)
    const unsigned short* ab = hbw + ((size_t)(b * 64 + gq * 16)) * 2048 + (size_t)lane * 8;
    // fallback f32 source (row = ml, k-chunk = kt*32+quad*8)
    const float*          fb = h   + ((size_t)(b * GS + grow0) + ml) * 128 + quad * 8;

    bf16x8_t afA[4];
    LOADA(afA, 0);
#pragma unroll
    for (int tl = 0; tl < 16; tl++) {
        f32x4_t c[4];
        MFMA_PHASE(afA);
        EPILOGUE(tl);
        if (tl < 15) LOADA(afA, tl + 1);   // after epilogue: no 2nd buffer live
    }
    __syncthreads();

    // drain this half's partials
    for (int e = t; e < 1024; e += 256) {
        int j = e >> 8, gl = e & 255;
        int tl = gl >> 4, row = gl & 15;
        float val = red[tl][(row >> 2) * 16 + (row & 3) * 4 + j];
        size_t idx = (size_t)b * 4096 + j * 1024 + grow0 + gl;
        if (HBF)
            FK2[(size_t)half * 1048576 + idx] = val;          // plain store
        else
            atomicAdd(&F[FK_RES + idx], val);                 // fallback
    }
}

// ---------------- kernel D: masked log-softmax + ll, (b,j) split ------------
template<int HBF>
__global__ __launch_bounds__(256) void finalize_kernel(
    const float* __restrict__ F, const float* __restrict__ FK2,
    const int* __restrict__ DESC, const int* __restrict__ vt,
    float* __restrict__ out)
{
    int bj = blockIdx.x;
    int b = bj >> 2, j = bj & 3;
    const int* dd = DESC + b * 32;
    if (j > 0 && dd[16 + j]) return;        // gated: zero contribution
    int t = threadIdx.x;
    int act0 = dd[0], la = dd[20], vt0 = dd[21];
    __shared__ float sred[8];
    __shared__ float schosen;

    int aj = dd[j];
    float lg[4];
#pragma unroll
    for (int q = 0; q < 4; q++) {
        int g = t + q * 256;
        bool neg;
        if (j == 0) {
            neg = (g == la);
        } else {
            int p = j - 1;
            int vtt = (vt[b * GS + g] - vt0) & (GS - 1);
            neg = (vtt <= dd[4 + p]) || (p == 0 && vtt > GS - 2);
            if (dd[8 + p] && g == dd[p]) neg = false;
            if (dd[12 + p] && g == act0) neg = false;
        }
        size_t idx = (size_t)b * 4096 + j * 1024 + g;
        float r = HBF ? (FK2[idx] + FK2[1048576 + idx]) : F[FK_RES + idx];
        float vv = neg ? NEGV : 6.0f * rtanh(r);
        lg[q] = vv;
        if (g == aj) schosen = vv;
    }
    float mx = fmaxf(fmaxf(lg[0], lg[1]), fmaxf(lg[2], lg[3]));
#pragma unroll
    for (int o = 1; o < 64; o <<= 1) mx = fmaxf(mx, __shfl_xor(mx, o));
    if ((t & 63) == 0) sred[t >> 6] = mx;
    __syncthreads();
    mx = fmaxf(fmaxf(sred[0], sred[1]), fmaxf(sred[2], sred[3]));
    float sm = 0.0f;
#pragma unroll
    for (int q = 0; q < 4; q++) sm += __expf(lg[q] - mx);
#pragma unroll
    for (int o = 1; o < 64; o <<= 1) sm += __shfl_xor(sm, o);
    if ((t & 63) == 0) sred[4 + (t >> 6)] = sm;
    __syncthreads();
    if (t == 0) {
        float tot = sred[4] + sred[5] + sred[6] + sred[7];
        float lse = mx + logf(tot);
        atomicAdd(&out[3072 + b], schosen - lse);
    }
}

extern "C" void kernel_launch(void* const* d_in, const int* in_sizes, int n_in,
                              void* d_out, int out_size, void* d_ws, size_t ws_size,
                              hipStream_t stream)
{
    (void)in_sizes; (void)n_in; (void)out_size;
    const float* h    = (const float*)d_in[0];
    const float* ctx2 = (const float*)d_in[1];
    const int*   rec  = (const int*)d_in[2];
    const int*   vtm  = (const int*)d_in[3];
    const int*   la   = (const int*)d_in[4];
    const int*   fa   = (const int*)d_in[5];
    const float* wk1 = (const float*)d_in[7];
    const float* wk2 = (const float*)d_in[8];
    const float* wk3 = (const float*)d_in[9];
    const float* wk4 = (const float*)d_in[10];
    const float* wq1 = (const float*)d_in[11];
    const float* wq2 = (const float*)d_in[12];
    const float* wq3 = (const float*)d_in[13];
    const float* wq4 = (const float*)d_in[14];
    const float* mW1 = (const float*)d_in[15];
    const float* mb1 = (const float*)d_in[16];
    const float* mW2 = (const float*)d_in[17];
    const float* mb2 = (const float*)d_in[18];
    const float* ihw = (const float*)d_in[19];
    const float* ihb = (const float*)d_in[20];
    const float* iq  = (const float*)d_in[21];
    const float* r1ih = (const float*)d_in[22];
    const float* r1hh = (const float*)d_in[23];
    const float* b1ih = (const float*)d_in[24];
    const float* b1hh = (const float*)d_in[25];
    const float* r2ih = (const float*)d_in[26];
    const float* r2hh = (const float*)d_in[27];
    const float* b2ih = (const float*)d_in[28];
    const float* b2hh = (const float*)d_in[29];

    unsigned short* wbf  = (unsigned short*)d_ws;
    unsigned short* wgru = (unsigned short*)((char*)d_ws + WGRU_OFF_BYTES);
    unsigned short* wqp  = (unsigned short*)((char*)d_ws + WQP_OFF_BYTES);
    unsigned short* wihb = (unsigned short*)((char*)d_ws + WIHB_OFF_BYTES);
    float* F   = (float*)((char*)d_ws + F_OFF_BYTES);
    int* DESC  = (int*)((char*)d_ws + DESC_OFF_BYTES);
    unsigned short* hbw = (unsigned short*)((char*)d_ws + HBF_OFF_BYTES);
    float* FK2 = (float*)((char*)d_ws + FK2_OFF_BYTES);
    float* out = (float*)d_out;

    int use_hbf = (ws_size >= WS_NEED) ? 1 : 0;

    init_kernel<<<dim3(2176), dim3(128), 0, stream>>>(h, wk1, wk2, wk3, wk4,
                                                      wq1, wq2, wq3, wq4, ihw,
                                                      r1ih, r1hh, r2ih, r2hh,
                                                      wbf, wgru, wqp, wihb, F,
                                                      hbw, use_hbf);
    prep_kernel<<<dim3(32), dim3(512), 0, stream>>>(h, ctx2, rec, vtm, la, fa,
                                                    mW1, mb1, mW2, mb2, ihb, iq,
                                                    b1ih, b1hh, b2ih, b2hh,
                                                    wgru, wqp, wihb, F, DESC, out);
    if (use_hbf) {
        score_kernel<1><<<dim3(2048), dim3(256), 0, stream>>>(h, hbw, wbf, F, FK2);
        finalize_kernel<1><<<dim3(1024), dim3(256), 0, stream>>>(F, FK2, DESC, vtm, out);
    } else {
        score_kernel<0><<<dim3(2048), dim3(256), 0, stream>>>(h, hbw, wbf, F, FK2);
        finalize_kernel<0><<<dim3(1024), dim3(256), 0, stream>>>(F, FK2, DESC, vtm, out);
    }
}

// Round 9
// 406.744 us; speedup vs baseline: 1.0862x; 1.0092x over previous
//
#include <hip/hip_runtime.h>
#include <hip/hip_bf16.h>
#include <math.h>

#define GS 1024
#define BSZ 256
#define DD 128
#define NEGV -1e30f

typedef __attribute__((ext_vector_type(8))) short bf16x8_t;
typedef __attribute__((ext_vector_type(4))) float f32x4_t;
typedef __attribute__((ext_vector_type(2))) float f32x2_t;

// ---- workspace layout (bytes) ---- (identical to proven 405us layout)
#define WGRU_OFF_BYTES 131072
#define WQP_OFF_BYTES  524288
#define WIHB_OFF_BYTES 655360
#define F_OFF_BYTES    688128
// float offsets inside F:
#define FH_HM   0        // 262144  h-mean partials [b][seg][d]
#define FI_V    262144   // 65536   [b][256] V1|V2
#define FJ_AQB  327680   // 524288  [b][d][j][sel]  sel = {a1,b1,a2,b2}
#define FK_RES  851968   // 1048576 [b][j][g]  (fallback path only)
#define F_TOTAL 1900544
#define DESC_OFF_BYTES (F_OFF_BYTES + F_TOTAL * 4)   // int [b][32]
// optional regions (only touched when ws_size >= WS_NEED):
// bf16 h image, MFMA-fragment-swizzled:
//   hbw[(((b*64 + T)*4 + kt)*64 + lane)*8 + j] = h[b][T*16 + (lane&15)][kt*32 + (lane>>4)*8 + j]
#define HBF_OFF_BYTES  (DESC_OFF_BYTES + 32768)      // 64 MB
#define FK2_OFF_BYTES  (HBF_OFF_BYTES + (size_t)BSZ * GS * DD * 2)  // 2x 4MB half-d partials
#define WS_NEED (FK2_OFF_BYTES + (size_t)2 * 1048576 * 4)

__device__ __forceinline__ float rtanh(float x) {
    float s = fmaf(x, x, 1.0f);
    return x * __builtin_amdgcn_rsqf(s);
}
__device__ __forceinline__ float tanh2(float x) {
    float e = __expf(x + x);
    return fmaf(-2.0f, __builtin_amdgcn_rcpf(e + 1.0f), 1.0f);
}
__device__ __forceinline__ float sigm2(float x) {
    return __builtin_amdgcn_rcpf(1.0f + __expf(-x));
}
__device__ __forceinline__ unsigned short f2bf(float f) {
    union { float f; unsigned u; } v; v.f = f;
    unsigned u = v.u;
    return (unsigned short)((u + 0x7fffu + ((u >> 16) & 1u)) >> 16);
}
// VALU-pipe cross-lane move (DPP). CTRL: 0xB1=xor1, 0x4E=xor2,
// 0x141=row_half_mirror(xor7), 0x140=row_mirror(xor15). All within
// 16-lane DPP rows == our quad groups.
template<int CTRL>
__device__ __forceinline__ float dppmov(float x) {
    union { float f; int i; } a, r; a.f = x;
    r.i = __builtin_amdgcn_mov_dpp(a.i, CTRL, 0xF, 0xF, false);
    return r.f;
}
#define MFMA16(a, b, c) __builtin_amdgcn_mfma_f32_16x16x32_bf16((a), (b), (c), 0, 0, 0)

// ---------------- kernel A: fused hmean (+ gated swizzled h->bf16) + pack ----
__global__ __launch_bounds__(128) void init_kernel(
    const float* __restrict__ h,
    const float* __restrict__ wk1, const float* __restrict__ wk2,
    const float* __restrict__ wk3, const float* __restrict__ wk4,
    const float* __restrict__ wq1, const float* __restrict__ wq2,
    const float* __restrict__ wq3, const float* __restrict__ wq4,
    const float* __restrict__ ihw,
    const float* __restrict__ r1ih, const float* __restrict__ r1hh,
    const float* __restrict__ r2ih, const float* __restrict__ r2hh,
    unsigned short* __restrict__ wbf, unsigned short* __restrict__ wgru,
    unsigned short* __restrict__ wqp, unsigned short* __restrict__ wihb,
    float* __restrict__ F, unsigned short* __restrict__ hbw, int use_hbf)
{
    if (blockIdx.x < 2048) {
        int b = blockIdx.x >> 3, seg = blockIdx.x & 7;
        int t = threadIdx.x;
        int rg = t >> 4, c = t & 15;
        int kt = c >> 2, quad = c & 3;
        // skewed LDS image: chunk q (16B) lives at byte (q + (q>>4)) * 16
        __shared__ __attribute__((aligned(16))) unsigned short lim[17408]; // 34816 B
        __shared__ float cs[8][128];
        float s0=0.f,s1=0.f,s2=0.f,s3=0.f,s4=0.f,s5=0.f,s6=0.f,s7=0.f;
#pragma unroll
        for (int i = 0; i < 16; i++) {
            int rl = rg + 8 * i;
            const float* src = h + ((size_t)(b * GS + seg * 128 + rl)) * DD + c * 8;
            f32x4_t lo = *(const f32x4_t*)src;
            f32x4_t hi = *(const f32x4_t*)(src + 4);
            s0 += lo[0]; s1 += lo[1]; s2 += lo[2]; s3 += lo[3];
            s4 += hi[0]; s5 += hi[1]; s6 += hi[2]; s7 += hi[3];
            if (use_hbf) {
                int tt = rl >> 4, ml = rl & 15;
                union { unsigned short s[8]; bf16x8_t v; } pk;
                pk.s[0] = f2bf(lo[0]); pk.s[1] = f2bf(lo[1]);
                pk.s[2] = f2bf(lo[2]); pk.s[3] = f2bf(lo[3]);
                pk.s[4] = f2bf(hi[0]); pk.s[5] = f2bf(hi[1]);
                pk.s[6] = f2bf(hi[2]); pk.s[7] = f2bf(hi[3]);
                int q = tt * 256 + kt * 64 + quad * 16 + ml;   // local chunk idx
                int ob16 = q + (q >> 4);                        // skew: +16B per 256B
                *(bf16x8_t*)&lim[ob16 * 8] = pk.v;
            }
        }
        cs[rg][c * 8 + 0] = s0; cs[rg][c * 8 + 1] = s1;
        cs[rg][c * 8 + 2] = s2; cs[rg][c * 8 + 3] = s3;
        cs[rg][c * 8 + 4] = s4; cs[rg][c * 8 + 5] = s5;
        cs[rg][c * 8 + 6] = s6; cs[rg][c * 8 + 7] = s7;
        __syncthreads();
        {
            int d = t;
            float s = 0.0f;
#pragma unroll
            for (int k = 0; k < 8; k++) s += cs[k][d];
            F[FH_HM + b * 1024 + seg * 128 + d] = s;
        }
        if (use_hbf) {
            unsigned short* dst = hbw + ((size_t)(b * 64 + seg * 8)) * 2048;
#pragma unroll
            for (int it = 0; it < 16; it++) {
                int e = it * 128 + t;
                int ob16 = e + (e >> 4);
                bf16x8_t v = *(const bf16x8_t*)&lim[ob16 * 8];
                *(bf16x8_t*)(dst + (size_t)e * 8) = v;   // linear, coalesced
            }
        }
        return;
    }
    int tid = (blockIdx.x - 2048) * 128 + threadIdx.x;
    int nth = 128 * 128;
    const float* wks[4]  = {wk1, wk2, wk3, wk4};
    const float* rws[4]  = {r1ih, r1hh, r2ih, r2hh};
    const float* wqs2[4] = {wq1, wq3, wq2, wq4};

    for (int e = tid; e < 65536; e += nth)            // W_K bf16 [mat][d][k]
        wbf[e] = f2bf(wks[e >> 14][e & 16383]);
    for (int e = tid; e < 196608; e += nth)           // GRU weights row-major
        wgru[e] = f2bf(rws[e / 49152][e % 49152]);
    for (int e = tid; e < 65536; e += nth)            // WQ pairs row-major
        wqp[e] = f2bf(wqs2[e >> 14][e & 16383]);
    for (int e = tid; e < 16384; e += nth)            // init_hidden_W row-major [d][k]
        wihb[e] = f2bf(ihw[e]);
    if (!use_hbf)
        for (int e = tid; e < 1048576; e += nth)      // zero FK_RES (fallback atomics)
            F[FK_RES + e] = 0.0f;
}

// ---------------- kernel B: fused prep + 4 GRU steps + AQ (proven version) ---
__global__ __launch_bounds__(512) void prep_kernel(
    const float* __restrict__ h, const float* __restrict__ ctx2,
    const int* __restrict__ rec, const int* __restrict__ vt,
    const int* __restrict__ la_, const int* __restrict__ fa,
    const float* __restrict__ mW1, const float* __restrict__ mb1,
    const float* __restrict__ mW2, const float* __restrict__ mb2,
    const float* __restrict__ ihb, const float* __restrict__ iq,
    const float* __restrict__ b1ih, const float* __restrict__ b1hh,
    const float* __restrict__ b2ih, const float* __restrict__ b2hh,
    const unsigned short* __restrict__ wgru, const unsigned short* __restrict__ wqp,
    const unsigned short* __restrict__ wihb,
    float* __restrict__ F, int* __restrict__ DESC, float* __restrict__ out)
{
    int rho = blockIdx.x & 1;
    int b0  = (blockIdx.x >> 1) * 16;
    int t = threadIdx.x;
    int lane = t & 63, w = t >> 6, ml = lane & 15, quad = lane >> 4;
    int dloc = w * 16 + ml;     // this lane's d

    __shared__ __attribute__((aligned(16))) unsigned short hmb[16][136];
    __shared__ __attribute__((aligned(16))) unsigned short Xall[4][16][136];
    __shared__ __attribute__((aligned(16))) unsigned short Qb[2][16][136];
    __shared__ float hid[16][8];
    __shared__ int sdesc[16][26];

    const float* bih = rho ? b2ih : b1ih;
    const float* bhh = rho ? b2hh : b1hh;

    // ---- phase 0: hm sums, meta hidden, int machine (independent) ----
#pragma unroll
    for (int k = 0; k < 4; k++) {
        int e = t + 512 * k;               // 2048 = 16b x 128d
        int b = e >> 7, d = e & 127;
        float s = 0.0f;
#pragma unroll
        for (int seg = 0; seg < 8; seg++)
            s += F[FH_HM + (b0 + b) * 1024 + seg * 128 + d];
        hmb[b][d] = f2bf(s * (1.0f / 1024.0f));
    }
    if (t < 128) {
        int b = t >> 3, u = t & 7;
        float a = mb1[u];
        for (int k = 0; k < 9; k++) a += mW1[u * 9 + k] * ctx2[(b0 + b) * 9 + k];
        hid[b][u] = a > 0.0f ? a : 0.0f;
    }
    if (rho == 0 && t >= 144 && t < 160)    // zero ll accumulators for finalize
        out[3072 + b0 + (t - 144)] = 0.0f;
    if (t >= 128 && t < 144) {
        int tb = t - 128;
        int b = b0 + tb;
        int ai[4], kal[5] = {0, 0, 0, 0, 0}, kar[4] = {0, 0, 0, 0};
        int idesc[26];
        int stopped = 1, nola = -1, vt0 = 0;
        for (int i = 0; i < 4; i++) {
            idesc[16 + i] = stopped;
            idesc[22 + i] = nola;
            int action = fa[b * 4 + i];
            if (i > 0 && stopped) action = ai[0];
            int nona = rec[b * GS + action];
            ai[i] = action;
            if (stopped) kal[i] = action;
            int jprev = (i + 3) & 3;
            if (!stopped) kar[jprev] = action;
            kal[i + 1] = nona;
            int hit = (action == nola) ? 1 : 0;
            int st = (i > 0) ? (stopped | hit) : hit;
            if (st) kal[i] = kal[(i + 4) % 5];
            if (st) kar[i] = kar[jprev];
            if (i == 0) vt0 = vt[b * GS + action];
            idesc[0 + i]  = action;
            idesc[4 + i]  = (vt[b * GS + action] - vt0) & (GS - 1);
            idesc[8 + i]  = st;
            idesc[12 + i] = (!st && (nona == ai[0])) ? 1 : 0;
            nola = st ? -1 : nona;
            stopped = st;
        }
        if (!stopped) kar[3] = kal[4];
        idesc[20] = la_[b];
        idesc[21] = vt0;
        int* dd = DESC + b * 32;
        for (int c = 0; c < 26; c++) { dd[c] = idesc[c]; sdesc[tb][c] = idesc[c]; }
        float* oa = out + b * 12;
        for (int c = 0; c < 4; c++) {
            oa[c]     = (float)ai[c];
            oa[4 + c] = (float)kal[c];
            oa[8 + c] = (float)kar[c];
        }
    }
    __syncthreads();

    // ---- phase 1: V, X-prefetch (needs sdesc), q0 (needs hmb) ----
#pragma unroll
    for (int k = 0; k < 8; k++) {
        int o = t + 512 * k;               // 4096 = 16b x 256
        int b = o >> 8, idx = o & 255;
        float a = mb2[idx];
#pragma unroll
        for (int u = 0; u < 8; u++) a += mW2[idx * 8 + u] * hid[b][u];
        F[FI_V + (b0 + b) * 256 + idx] = a;
    }
    for (int e = t; e < 2048; e += 512) {  // step 0: iq broadcast to 16 rows
        int row = e >> 7, d = e & 127;
        Xall[0][row][d] = f2bf(iq[d]);
    }
    for (int e = t; e < 6144; e += 512) {  // steps 1..3 gathered rows
        int i = (e >> 11) + 1;
        int b = (e >> 7) & 15, d = e & 127;
        int a = sdesc[b][i - 1];
        int srcrow = a;
        if (rho) {
            int sE = sdesc[b][16 + (i - 1)];
            int nl = sdesc[b][22 + (i - 1)];
            srcrow = sE ? a : (nl & (GS - 1));
        }
        Xall[i][b][d] = f2bf(h[((size_t)((b0 + b) * GS + srcrow)) * DD + d]);
    }
    // q0 = hm @ ihw^T + ihb (wave w covers n = w*16..w*16+16)
    float qreg[4];
    {
        bf16x8_t am[4];
#pragma unroll
        for (int kt = 0; kt < 4; kt++)
            am[kt] = *(const bf16x8_t*)&hmb[ml][kt * 32 + quad * 8];
        const unsigned short* wb = wihb + (size_t)dloc * 128 + quad * 8;
        f32x4_t acc = {0.f, 0.f, 0.f, 0.f};
#pragma unroll
        for (int kt = 0; kt < 4; kt++)
            acc = MFMA16(am[kt], *(const bf16x8_t*)(wb + kt * 32), acc);
        float bias = ihb[dloc];
#pragma unroll
        for (int r_ = 0; r_ < 4; r_++) {
            qreg[r_] = acc[r_] + bias;
            Qb[0][quad * 4 + r_][dloc] = f2bf(qreg[r_]);
        }
    }
    __syncthreads();

    // ---- phase 2: 4 GRU steps + AQ, one barrier per step ----
    float bir = bih[dloc], biz = bih[128 + dloc], bin_ = bih[256 + dloc];
    float bhr = bhh[dloc], bhz = bhh[128 + dloc], bhn = bhh[256 + dloc];

    for (int i = 0; i < 4; i++) {
        int cur = i & 1;
        bf16x8_t ax[4], aq[4];
#pragma unroll
        for (int kt = 0; kt < 4; kt++) {
            ax[kt] = *(const bf16x8_t*)&Xall[i][ml][kt * 32 + quad * 8];
            aq[kt] = *(const bf16x8_t*)&Qb[cur][ml][kt * 32 + quad * 8];
        }
        f32x4_t gi[3], gh[3];
#pragma unroll
        for (int gate = 0; gate < 3; gate++) {
            int n = gate * 128 + dloc;
            const unsigned short* wi = wgru + ((size_t)((rho * 2 + 0) * 384 + n)) * 128 + quad * 8;
            const unsigned short* wh = wgru + ((size_t)((rho * 2 + 1) * 384 + n)) * 128 + quad * 8;
            f32x4_t ai = {0.f, 0.f, 0.f, 0.f}, ah = {0.f, 0.f, 0.f, 0.f};
#pragma unroll
            for (int kt = 0; kt < 4; kt++) {
                ai = MFMA16(ax[kt], *(const bf16x8_t*)(wi + kt * 32), ai);
                ah = MFMA16(aq[kt], *(const bf16x8_t*)(wh + kt * 32), ah);
            }
            gi[gate] = ai; gh[gate] = ah;
        }
#pragma unroll
        for (int r_ = 0; r_ < 4; r_++) {
            float r = sigm2(gi[0][r_] + bir + gh[0][r_] + bhr);
            float z = sigm2(gi[1][r_] + biz + gh[1][r_] + bhz);
            float n = tanh2(gi[2][r_] + bin_ + r * (gh[2][r_] + bhn));
            qreg[r_] = fmaf(z, qreg[r_] - n, n);
            Qb[cur ^ 1][quad * 4 + r_][dloc] = f2bf(qreg[r_]);
        }
        __syncthreads();

        // AQ projection from q' (reads Qb[cur^1])
        bf16x8_t aqn[4];
#pragma unroll
        for (int kt = 0; kt < 4; kt++)
            aqn[kt] = *(const bf16x8_t*)&Qb[cur ^ 1][ml][kt * 32 + quad * 8];
#pragma unroll
        for (int half = 0; half < 2; half++) {
            int nrow = half * 128 + dloc;
            const unsigned short* wq = wqp + ((size_t)(rho * 256 + nrow)) * 128 + quad * 8;
            f32x4_t acc = {0.f, 0.f, 0.f, 0.f};
#pragma unroll
            for (int kt = 0; kt < 4; kt++)
                acc = MFMA16(aqn[kt], *(const bf16x8_t*)(wq + kt * 32), acc);
            int sel = rho * 2 + half;
#pragma unroll
            for (int r_ = 0; r_ < 4; r_++) {
                int b2 = b0 + quad * 4 + r_;
                F[FJ_AQB + b2 * 2048 + dloc * 16 + i * 4 + sel] = acc[r_];
            }
        }
    }
}

// ---------------- kernel C: barrier-free score, DPP butterfly ---------------
// grid 2048 = (b, gq 0..3, half 0..1); 256 thr = 4 waves, launch_bounds(256,3).
// The d-reduction butterfly runs entirely on the VALU pipe via DPP
// (levels xor15, xor7, xor2, xor1) — zero ds_bpermute. R4/R7 both pinned
// VALUBusy at 50% because 15 shfl/tile/wave saturated the CU's shared DS
// unit. Slot mapping re-derived: lane ml ends with (r,j) where
// j = ml3|(ml2<<1), r = ml1|(ml0<<1); drain below inverts it.
#define LOADA(dst, TL) do {                                                    \
    if (HBF) {                                                                 \
        _Pragma("unroll")                                                      \
        for (int kt = 0; kt < 4; kt++)                                         \
            dst[kt] = *(const bf16x8_t*)(ab + (size_t)(TL) * 2048 + kt * 512); \
    } else {                                                                   \
        _Pragma("unroll")                                                      \
        for (int kt = 0; kt < 4; kt++) {                                       \
            f32x4_t lo = *(const f32x4_t*)(fb + (size_t)(TL) * 2048 + kt * 32);     \
            f32x4_t hi = *(const f32x4_t*)(fb + (size_t)(TL) * 2048 + kt * 32 + 4); \
            union { unsigned short s[8]; bf16x8_t v; } pk_;                    \
            pk_.s[0] = f2bf(lo[0]); pk_.s[1] = f2bf(lo[1]);                    \
            pk_.s[2] = f2bf(lo[2]); pk_.s[3] = f2bf(lo[3]);                    \
            pk_.s[4] = f2bf(hi[0]); pk_.s[5] = f2bf(hi[1]);                    \
            pk_.s[6] = f2bf(hi[2]); pk_.s[7] = f2bf(hi[3]);                    \
            dst[kt] = pk_.v;                                                   \
        }                                                                      \
    }                                                                          \
} while (0)

#define MFMA_PHASE(af) do {                                                    \
    _Pragma("unroll") for (int m_ = 0; m_ < 4; m_++)                           \
        c[m_] = (f32x4_t){0.f, 0.f, 0.f, 0.f};                                 \
    _Pragma("unroll") for (int kt = 0; kt < 4; kt++) {                         \
        _Pragma("unroll") for (int m_ = 0; m_ < 4; m_++)                       \
            c[m_] = MFMA16(af[kt], bfr[m_][kt], c[m_]);                        \
    }                                                                          \
} while (0)

// DPP butterfly epilogue. Per r: levels xor15 (b=ml>>3), xor7 (b=ml>>2)
// reduce over j; across r: xor2 (b=ml>>1), xor1 (b=ml&1).
#define EPILOGUE(TL) do {                                                      \
    float w0_, w1_, w2_, w3_;                                                  \
    _Pragma("unroll") for (int r_ = 0; r_ < 4; r_++) {                         \
        f32x2_t cA = {c[0][r_], c[1][r_]};                                     \
        f32x2_t cM = {c[2][r_], c[3][r_]};                                     \
        float u_[4];                                                           \
        _Pragma("unroll") for (int j_ = 0; j_ < 4; j_++) {                     \
            f32x2_t y = cA + aa[j_] + cM * bb[j_];                             \
            f32x2_t s = y * y + (f32x2_t){1.0f, 1.0f};                         \
            f32x2_t rs = {__builtin_amdgcn_rsqf(s[0]), __builtin_amdgcn_rsqf(s[1])}; \
            f32x2_t tv = y * rs * VV;                                          \
            u_[j_] = tv[0] + tv[1];                                            \
        }                                                                      \
        float p0_, p1_;                                                        \
        { int bs = (ml >> 3) & 1;   /* level xor15 = row_mirror */             \
          p0_ = (bs ? u_[1] : u_[0]) + dppmov<0x140>(bs ? u_[0] : u_[1]);      \
          p1_ = (bs ? u_[3] : u_[2]) + dppmov<0x140>(bs ? u_[2] : u_[3]); }    \
        float wr_;                                                             \
        { int bs = (ml >> 2) & 1;   /* level xor7 = row_half_mirror */         \
          wr_ = (bs ? p1_ : p0_) + dppmov<0x141>(bs ? p0_ : p1_); }            \
        if (r_ == 0) w0_ = wr_; else if (r_ == 1) w1_ = wr_;                   \
        else if (r_ == 2) w2_ = wr_; else w3_ = wr_;                           \
    }                                                                          \
    float q0_, q1_, v0_;                                                       \
    { int bs = (ml >> 1) & 1;       /* level xor2 = quad_perm(2,3,0,1) */      \
      q0_ = (bs ? w1_ : w0_) + dppmov<0x4E>(bs ? w0_ : w1_);                   \
      q1_ = (bs ? w3_ : w2_) + dppmov<0x4E>(bs ? w2_ : w3_); }                 \
    { int bs = ml & 1;              /* level xor1 = quad_perm(1,0,3,2) */      \
      v0_ = (bs ? q1_ : q0_) + dppmov<0xB1>(bs ? q0_ : q1_); }                 \
    atomicAdd(&red[TL][quad * 16 + ml], v0_);                                  \
} while (0)

template<int HBF>
__global__ __launch_bounds__(256, 3) void score_kernel(
    const float* __restrict__ h, const unsigned short* __restrict__ hbw,
    const unsigned short* __restrict__ wbf, float* __restrict__ F,
    float* __restrict__ FK2)
{
    int bid = blockIdx.x;
    int half = bid & 1, gq = (bid >> 1) & 3, b = bid >> 3;
    int t = threadIdx.x;
    int lane = t & 63, w = t >> 6;          // w 0..3
    int ml = lane & 15, quad = lane >> 4;
    int dg = half * 64 + w * 16 + ml;       // this lane's output-d column

    __shared__ float red[16][64];           // per-tile partial sums (DPP-slot order)
    for (int e = t; e < 1024; e += 256) ((float*)red)[e] = 0.0f;

    // persistent per-lane B-fragments, pinned (R3/R4 evidence: keeps them
    // resident in the unified file instead of scratch)
    bf16x8_t bfr[4][4];
#pragma unroll
    for (int mat = 0; mat < 4; mat++)
#pragma unroll
        for (int kt = 0; kt < 4; kt++)
            bfr[mat][kt] = *(const bf16x8_t*)(wbf + ((size_t)(mat * 128 + dg)) * 128 + kt * 32 + quad * 8);
#pragma unroll
    for (int mat = 0; mat < 4; mat++)
#pragma unroll
        for (int kt = 0; kt < 4; kt++)
            asm volatile("" : "+v"(bfr[mat][kt]));

    const float* Vb = F + FI_V + b * 256;
    f32x2_t VV = {Vb[dg], Vb[128 + dg]};
    const float* AQ = F + FJ_AQB + b * 2048 + dg * 16;
    f32x2_t aa[4], bb[4];
#pragma unroll
    for (int j = 0; j < 4; j++) {
        f32x4_t q = *(const f32x4_t*)(AQ + j * 4);   // {a1,b1,a2,b2}
        aa[j] = (f32x2_t){q[0], q[2]};
        bb[j] = (f32x2_t){q[1], q[3]};
    }

    __syncthreads();   // red zero-init visible to all waves

    int grow0 = gq * 256;
    // swizzled per-lane A source: tile base + lane*16B (coalesced)
    const unsigned short* ab = hbw + ((size_t)(b * 64 + gq * 16)) * 2048 + (size_t)lane * 8;
    // fallback f32 source (row = ml, k-chunk = kt*32+quad*8)
    const float*          fb = h   + ((size_t)(b * GS + grow0) + ml) * 128 + quad * 8;

    bf16x8_t afA[4];
    LOADA(afA, 0);
#pragma unroll
    for (int tl = 0; tl < 16; tl++) {
        f32x4_t c[4];
        MFMA_PHASE(afA);
        if (tl < 15) LOADA(afA, tl + 1);   // latency hides under DPP epilogue
        EPILOGUE(tl);
    }
    __syncthreads();

    // drain this half's partials. DPP-slot inverse: value for (row-r, j)
    // sits at lane ml = ((j&1)<<3)|((j&2)<<1)|((r&1)<<1)|((r>>1)&1).
    for (int e = t; e < 1024; e += 256) {
        int j = e >> 8, gl = e & 255;
        int tl = gl >> 4, row = gl & 15;
        int r = row & 3;
        int mlidx = ((j & 1) << 3) | ((j & 2) << 1) | ((r & 1) << 1) | ((r >> 1) & 1);
        float val = red[tl][(row >> 2) * 16 + mlidx];
        size_t idx = (size_t)b * 4096 + j * 1024 + grow0 + gl;
        if (HBF)
            FK2[(size_t)half * 1048576 + idx] = val;          // plain store
        else
            atomicAdd(&F[FK_RES + idx], val);                 // fallback
    }
}

// ---------------- kernel D: masked log-softmax + ll, (b,j) split ------------
template<int HBF>
__global__ __launch_bounds__(256) void finalize_kernel(
    const float* __restrict__ F, const float* __restrict__ FK2,
    const int* __restrict__ DESC, const int* __restrict__ vt,
    float* __restrict__ out)
{
    int bj = blockIdx.x;
    int b = bj >> 2, j = bj & 3;
    const int* dd = DESC + b * 32;
    if (j > 0 && dd[16 + j]) return;        // gated: zero contribution
    int t = threadIdx.x;
    int act0 = dd[0], la = dd[20], vt0 = dd[21];
    __shared__ float sred[8];
    __shared__ float schosen;

    int aj = dd[j];
    float lg[4];
#pragma unroll
    for (int q = 0; q < 4; q++) {
        int g = t + q * 256;
        bool neg;
        if (j == 0) {
            neg = (g == la);
        } else {
            int p = j - 1;
            int vtt = (vt[b * GS + g] - vt0) & (GS - 1);
            neg = (vtt <= dd[4 + p]) || (p == 0 && vtt > GS - 2);
            if (dd[8 + p] && g == dd[p]) neg = false;
            if (dd[12 + p] && g == act0) neg = false;
        }
        size_t idx = (size_t)b * 4096 + j * 1024 + g;
        float r = HBF ? (FK2[idx] + FK2[1048576 + idx]) : F[FK_RES + idx];
        float vv = neg ? NEGV : 6.0f * rtanh(r);
        lg[q] = vv;
        if (g == aj) schosen = vv;
    }
    float mx = fmaxf(fmaxf(lg[0], lg[1]), fmaxf(lg[2], lg[3]));
#pragma unroll
    for (int o = 1; o < 64; o <<= 1) mx = fmaxf(mx, __shfl_xor(mx, o));
    if ((t & 63) == 0) sred[t >> 6] = mx;
    __syncthreads();
    mx = fmaxf(fmaxf(sred[0], sred[1]), fmaxf(sred[2], sred[3]));
    float sm = 0.0f;
#pragma unroll
    for (int q = 0; q < 4; q++) sm += __expf(lg[q] - mx);
#pragma unroll
    for (int o = 1; o < 64; o <<= 1) sm += __shfl_xor(sm, o);
    if ((t & 63) == 0) sred[4 + (t >> 6)] = sm;
    __syncthreads();
    if (t == 0) {
        float tot = sred[4] + sred[5] + sred[6] + sred[7];
        float lse = mx + logf(tot);
        atomicAdd(&out[3072 + b], schosen - lse);
    }
}

extern "C" void kernel_launch(void* const* d_in, const int* in_sizes, int n_in,
                              void* d_out, int out_size, void* d_ws, size_t ws_size,
                              hipStream_t stream)
{
    (void)in_sizes; (void)n_in; (void)out_size;
    const float* h    = (const float*)d_in[0];
    const float* ctx2 = (const float*)d_in[1];
    const int*   rec  = (const int*)d_in[2];
    const int*   vtm  = (const int*)d_in[3];
    const int*   la   = (const int*)d_in[4];
    const int*   fa   = (const int*)d_in[5];
    const float* wk1 = (const float*)d_in[7];
    const float* wk2 = (const float*)d_in[8];
    const float* wk3 = (const float*)d_in[9];
    const float* wk4 = (const float*)d_in[10];
    const float* wq1 = (const float*)d_in[11];
    const float* wq2 = (const float*)d_in[12];
    const float* wq3 = (const float*)d_in[13];
    const float* wq4 = (const float*)d_in[14];
    const float* mW1 = (const float*)d_in[15];
    const float* mb1 = (const float*)d_in[16];
    const float* mW2 = (const float*)d_in[17];
    const float* mb2 = (const float*)d_in[18];
    const float* ihw = (const float*)d_in[19];
    const float* ihb = (const float*)d_in[20];
    const float* iq  = (const float*)d_in[21];
    const float* r1ih = (const float*)d_in[22];
    const float* r1hh = (const float*)d_in[23];
    const float* b1ih = (const float*)d_in[24];
    const float* b1hh = (const float*)d_in[25];
    const float* r2ih = (const float*)d_in[26];
    const float* r2hh = (const float*)d_in[27];
    const float* b2ih = (const float*)d_in[28];
    const float* b2hh = (const float*)d_in[29];

    unsigned short* wbf  = (unsigned short*)d_ws;
    unsigned short* wgru = (unsigned short*)((char*)d_ws + WGRU_OFF_BYTES);
    unsigned short* wqp  = (unsigned short*)((char*)d_ws + WQP_OFF_BYTES);
    unsigned short* wihb = (unsigned short*)((char*)d_ws + WIHB_OFF_BYTES);
    float* F   = (float*)((char*)d_ws + F_OFF_BYTES);
    int* DESC  = (int*)((char*)d_ws + DESC_OFF_BYTES);
    unsigned short* hbw = (unsigned short*)((char*)d_ws + HBF_OFF_BYTES);
    float* FK2 = (float*)((char*)d_ws + FK2_OFF_BYTES);
    float* out = (float*)d_out;

    int use_hbf = (ws_size >= WS_NEED) ? 1 : 0;

    init_kernel<<<dim3(2176), dim3(128), 0, stream>>>(h, wk1, wk2, wk3, wk4,
                                                      wq1, wq2, wq3, wq4, ihw,
                                                      r1ih, r1hh, r2ih, r2hh,
                                                      wbf, wgru, wqp, wihb, F,
                                                      hbw, use_hbf);
    prep_kernel<<<dim3(32), dim3(512), 0, stream>>>(h, ctx2, rec, vtm, la, fa,
                                                    mW1, mb1, mW2, mb2, ihb, iq,
                                                    b1ih, b1hh, b2ih, b2hh,
                                                    wgru, wqp, wihb, F, DESC, out);
    if (use_hbf) {
        score_kernel<1><<<dim3(2048), dim3(256), 0, stream>>>(h, hbw, wbf, F, FK2);
        finalize_kernel<1><<<dim3(1024), dim3(256), 0, stream>>>(F, FK2, DESC, vtm, out);
    } else {
        score_kernel<0><<<dim3(2048), dim3(256), 0, stream>>>(h, hbw, wbf, F, FK2);
        finalize_kernel<0><<<dim3(1024), dim3(256), 0, stream>>>(F, FK2, DESC, vtm, out);
    }
}